// Round 1
// baseline (636.617 us; speedup 1.0000x reference)
//
#include <hip/hip_runtime.h>
#include <math.h>

// WinGNN forward on MI355X — f32 throughout (no fp32 MFMA on CDNA4; bf16-MFMA
// is a later experiment gated on validation tolerance).
//
// Pipeline (all on `stream`, graph-capture safe):
//  1. k_init      : deg=1 (self-loop), indeg=0
//  2. k_count     : atomic degree counts by row (norm) and col (CSR build)
//  3. k_scan      : single-block exclusive scan -> colptr/cursor; dinv=1/sqrt(deg)
//  4. k_fill      : CSR fill (csrc[pos] = row[e]) via atomic cursor
//  5. k_transform : h = relu(x @ W1^T + b1)          [LDS-tiled f32 GEMM]
//  6. k_agg<1>    : hn = A(h);  hidden = h + hn      [half-wave per node gather]
//     k_agg<0>    : h2 = A(hn); hidden += h2         (h2 reuses h buffer)
//  7. k_norm      : hidden row-L2-normalize in place
//  8. k_pred_init : pred[e] = b_l2
//  9. k_head      : pred[e] += sum_o Wl2[o]*relu(b_l1[o] + cat(hid_i,hid_j)@Wl1[o])
//                   [LDS-tiled, K split 128+128 (= x_i then x_j), o-halves atomicAdd]

#define NN 50000
#define NE 500000
#define NL 100000

__global__ __launch_bounds__(256) void k_init(int* __restrict__ deg,
                                              int* __restrict__ indeg) {
  int i = blockIdx.x * 256 + threadIdx.x;
  if (i < NN) { deg[i] = 1; indeg[i] = 0; }
}

__global__ __launch_bounds__(256) void k_count(const int* __restrict__ ei,
                                               int* __restrict__ deg,
                                               int* __restrict__ indeg) {
  int e = blockIdx.x * 256 + threadIdx.x;
  if (e < NE) {
    atomicAdd(&deg[ei[e]], 1);        // row -> deg (normalization)
    atomicAdd(&indeg[ei[NE + e]], 1); // col -> indeg (CSR)
  }
}

__global__ __launch_bounds__(1024) void k_scan(const int* __restrict__ indeg,
                                               const int* __restrict__ deg,
                                               float* __restrict__ dinv,
                                               int* __restrict__ colptr,
                                               int* __restrict__ cursor) {
  __shared__ int lds[1024];
  int tid = threadIdx.x;
  for (int i = tid; i < NN; i += 1024)
    dinv[i] = 1.0f / sqrtf((float)deg[i]);  // deg >= 1 always (self loop)

  const int C = (NN + 1023) / 1024;  // 49
  int base = tid * C;
  int sum = 0;
  for (int r = 0; r < C; ++r) {
    int idx = base + r;
    if (idx < NN) sum += indeg[idx];
  }
  lds[tid] = sum;
  __syncthreads();
  // Hillis-Steele inclusive scan over 1024 partials
  for (int s = 1; s < 1024; s <<= 1) {
    int v = (tid >= s) ? lds[tid - s] : 0;
    __syncthreads();
    lds[tid] += v;
    __syncthreads();
  }
  int run = lds[tid] - sum;  // exclusive prefix
  for (int r = 0; r < C; ++r) {
    int idx = base + r;
    if (idx < NN) {
      colptr[idx] = run;
      cursor[idx] = run;
      run += indeg[idx];
    }
  }
  if (tid == 1023) colptr[NN] = run;  // == NE
}

__global__ __launch_bounds__(256) void k_fill(const int* __restrict__ ei,
                                              int* __restrict__ cursor,
                                              int* __restrict__ csrc) {
  int e = blockIdx.x * 256 + threadIdx.x;
  if (e < NE) {
    int c = ei[NE + e];
    int pos = atomicAdd(&cursor[c], 1);
    csrc[pos] = ei[e];
  }
}

// ---------------- transform: h = relu(x @ W1^T + b1) ----------------
// block = 128 thr (2 waves). Tile: 32 nodes x 64 outs, K=128 fully in LDS.
// WT[k][o'] stride 68 (write 8-way ok, b128 read conflict-free, 16B aligned)
// XT[k][m]  stride 36 (same properties)
__global__ __launch_bounds__(128) void k_transform(const float* __restrict__ x,
                                                   const float* __restrict__ W1,
                                                   const float* __restrict__ b1,
                                                   float* __restrict__ h) {
  __shared__ float WT[128 * 68];
  __shared__ float XT[128 * 36];
  int bid = blockIdx.x;
  int ohalf = bid & 1;
  int n0 = (bid >> 1) * 32;
  int obase = ohalf * 64;
  int tid = threadIdx.x;

  for (int idx = tid; idx < 64 * 128; idx += 128) {
    int o = idx >> 7, k = idx & 127;
    WT[k * 68 + o] = W1[(obase + o) * 128 + k];
  }
  for (int idx = tid; idx < 32 * 128; idx += 128) {
    int m = idx >> 7, k = idx & 127;
    int node = n0 + m;
    XT[k * 36 + m] = (node < NN) ? x[node * 128 + k] : 0.0f;
  }
  __syncthreads();

  int lane = tid & 63, w = tid >> 6;
  int oi = lane & 15, mi = lane >> 4;
  int mloc = w * 16 + mi * 4;
  float acc[4][4] = {};
#pragma unroll 4
  for (int k = 0; k < 128; ++k) {
    float4 w4 = *(const float4*)&WT[k * 68 + 4 * oi];
    float4 x4 = *(const float4*)&XT[k * 36 + mloc];
    float wv[4] = {w4.x, w4.y, w4.z, w4.w};
    float xv[4] = {x4.x, x4.y, x4.z, x4.w};
#pragma unroll
    for (int a = 0; a < 4; ++a)
#pragma unroll
      for (int b = 0; b < 4; ++b) acc[a][b] += xv[a] * wv[b];
  }

  int o0 = obase + oi * 4;
  float4 b4 = *(const float4*)&b1[o0];
  float bv[4] = {b4.x, b4.y, b4.z, b4.w};
#pragma unroll
  for (int a = 0; a < 4; ++a) {
    int node = n0 + mloc + a;
    if (node < NN) {
      float4 r;
      r.x = fmaxf(acc[a][0] + bv[0], 0.0f);
      r.y = fmaxf(acc[a][1] + bv[1], 0.0f);
      r.z = fmaxf(acc[a][2] + bv[2], 0.0f);
      r.w = fmaxf(acc[a][3] + bv[3], 0.0f);
      *(float4*)&h[node * 128 + o0] = r;
    }
  }
}

// ---------------- aggregation hop ----------------
// half-wave (32 lanes x float4) per node:
// out[v] = dinv[v] * ( sum_in dinv[src]*in[src] + dinv[v]*in[v] )
// FIRST hop: hidden = in[v] + out ; else hidden += out
template <int FIRST>
__global__ __launch_bounds__(256) void k_agg(const float* __restrict__ in,
                                             float* __restrict__ out,
                                             float* __restrict__ hidden,
                                             const float* __restrict__ dinv,
                                             const int* __restrict__ colptr,
                                             const int* __restrict__ csrc) {
  int v = (blockIdx.x * 256 + threadIdx.x) >> 5;
  int l = threadIdx.x & 31;
  if (v >= NN) return;
  float dv = dinv[v];
  float4 sv = *(const float4*)(in + v * 128 + l * 4);
  float ax = sv.x * dv, ay = sv.y * dv, az = sv.z * dv, aw = sv.w * dv;
  int s = colptr[v], e = colptr[v + 1];
  for (int p = s; p < e; ++p) {
    int src = csrc[p];
    float ds = dinv[src];
    float4 hs = *(const float4*)(in + src * 128 + l * 4);
    ax += hs.x * ds; ay += hs.y * ds; az += hs.z * ds; aw += hs.w * ds;
  }
  ax *= dv; ay *= dv; az *= dv; aw *= dv;
  float4 o4 = {ax, ay, az, aw};
  *(float4*)(out + v * 128 + l * 4) = o4;
  float4 hd;
  if (FIRST) {
    hd = {sv.x + ax, sv.y + ay, sv.z + az, sv.w + aw};
  } else {
    float4 hp = *(const float4*)(hidden + v * 128 + l * 4);
    hd = {hp.x + ax, hp.y + ay, hp.z + az, hp.w + aw};
  }
  *(float4*)(hidden + v * 128 + l * 4) = hd;
}

// ---------------- row L2 normalize ----------------
__global__ __launch_bounds__(256) void k_norm(float* __restrict__ hidden) {
  int v = (blockIdx.x * 256 + threadIdx.x) >> 5;
  int l = threadIdx.x & 31;
  if (v >= NN) return;
  float4 hv = *(const float4*)(hidden + v * 128 + l * 4);
  float ss = hv.x * hv.x + hv.y * hv.y + hv.z * hv.z + hv.w * hv.w;
#pragma unroll
  for (int s = 1; s < 32; s <<= 1) ss += __shfl_xor(ss, s, 64);
  float nrm = sqrtf(ss);
  float sc = 1.0f / fmaxf(nrm, 1e-12f);
  float4 r = {hv.x * sc, hv.y * sc, hv.z * sc, hv.w * sc};
  *(float4*)(hidden + v * 128 + l * 4) = r;
}

__global__ __launch_bounds__(256) void k_pred_init(float* __restrict__ pred,
                                                   const float* __restrict__ bl2) {
  int e = blockIdx.x * 256 + threadIdx.x;
  if (e < NL) pred[e] = bl2[0];
}

// ---------------- head ----------------
// block = 128 thr, tile 32 edges x 64 outs (o-half), K=256 in 2 chunks of 128
// (chunk 0 = hidden[i], chunk 1 = hidden[j]). Fused relu+dot(Wl2) epilogue,
// 16-lane shuffle reduce, atomicAdd per (edge, o-half).
__global__ __launch_bounds__(128) void k_head(const float* __restrict__ hidden,
                                              const float* __restrict__ Wl1,
                                              const float* __restrict__ bl1,
                                              const float* __restrict__ Wl2,
                                              const int* __restrict__ eli,
                                              float* __restrict__ pred) {
  __shared__ float WT[128 * 68];
  __shared__ float CT[128 * 36];
  int bid = blockIdx.x;
  int ohalf = bid & 1;
  int e0 = (bid >> 1) * 32;
  int obase = ohalf * 64;
  int tid = threadIdx.x;
  int lane = tid & 63, w = tid >> 6;
  int oi = lane & 15, mi = lane >> 4;
  int mloc = w * 16 + mi * 4;
  float acc[4][4] = {};

  for (int kc = 0; kc < 2; ++kc) {
    __syncthreads();
    for (int idx = tid; idx < 64 * 128; idx += 128) {
      int o = idx >> 7, k = idx & 127;
      WT[k * 68 + o] = Wl1[(obase + o) * 256 + kc * 128 + k];
    }
    for (int it = 0; it < 32; ++it) {
      int node = eli[kc * NL + e0 + it];
      CT[tid * 36 + it] = hidden[node * 128 + tid];
    }
    __syncthreads();
#pragma unroll 4
    for (int k = 0; k < 128; ++k) {
      float4 w4 = *(const float4*)&WT[k * 68 + 4 * oi];
      float4 c4 = *(const float4*)&CT[k * 36 + mloc];
      float wv[4] = {w4.x, w4.y, w4.z, w4.w};
      float cv[4] = {c4.x, c4.y, c4.z, c4.w};
#pragma unroll
      for (int a = 0; a < 4; ++a)
#pragma unroll
        for (int b = 0; b < 4; ++b) acc[a][b] += cv[a] * wv[b];
    }
  }

  int o0 = obase + oi * 4;
  float4 b4 = *(const float4*)&bl1[o0];
  float4 w2 = *(const float4*)&Wl2[o0];
  float bv[4] = {b4.x, b4.y, b4.z, b4.w};
  float wv2[4] = {w2.x, w2.y, w2.z, w2.w};
#pragma unroll
  for (int a = 0; a < 4; ++a) {
    float part = 0.0f;
#pragma unroll
    for (int b = 0; b < 4; ++b)
      part += fmaxf(acc[a][b] + bv[b], 0.0f) * wv2[b];
#pragma unroll
    for (int s = 1; s < 16; s <<= 1) part += __shfl_xor(part, s, 64);
    if (oi == 0) atomicAdd(&pred[e0 + mloc + a], part);
  }
}

extern "C" void kernel_launch(void* const* d_in, const int* in_sizes, int n_in,
                              void* d_out, int out_size, void* d_ws, size_t ws_size,
                              hipStream_t stream) {
  const float* x   = (const float*)d_in[0];
  const float* W1  = (const float*)d_in[1];
  const float* b1  = (const float*)d_in[2];
  const float* Wl1 = (const float*)d_in[3];
  const float* bl1 = (const float*)d_in[4];
  const float* Wl2 = (const float*)d_in[5];
  const float* bl2 = (const float*)d_in[6];
  const int* ei    = (const int*)d_in[7];
  const int* eli   = (const int*)d_in[8];
  float* pred = (float*)d_out;

  char* ws = (char*)d_ws;
  size_t off = 0;
  auto alloc = [&](size_t bytes) {
    void* p = ws + off;
    off = (off + bytes + 255) & ~(size_t)255;
    return p;
  };
  float* dinv  = (float*)alloc(NN * 4);
  int* deg     = (int*)alloc(NN * 4);
  int* indeg   = (int*)alloc(NN * 4);
  int* colptr  = (int*)alloc((NN + 1) * 4);
  int* cursor  = (int*)alloc(NN * 4);
  int* csrc    = (int*)alloc((size_t)NE * 4);
  float* h     = (float*)alloc((size_t)NN * 128 * 4);
  float* hn    = (float*)alloc((size_t)NN * 128 * 4);
  float* hid   = (float*)alloc((size_t)NN * 128 * 4);

  k_init<<<(NN + 255) / 256, 256, 0, stream>>>(deg, indeg);
  k_count<<<(NE + 255) / 256, 256, 0, stream>>>(ei, deg, indeg);
  k_scan<<<1, 1024, 0, stream>>>(indeg, deg, dinv, colptr, cursor);
  k_fill<<<(NE + 255) / 256, 256, 0, stream>>>(ei, cursor, csrc);

  k_transform<<<((NN + 31) / 32) * 2, 128, 0, stream>>>(x, W1, b1, h);

  k_agg<1><<<(NN * 32 + 255) / 256, 256, 0, stream>>>(h, hn, hid, dinv, colptr, csrc);
  k_agg<0><<<(NN * 32 + 255) / 256, 256, 0, stream>>>(hn, h, hid, dinv, colptr, csrc);

  k_norm<<<(NN * 32 + 255) / 256, 256, 0, stream>>>(hid);

  k_pred_init<<<(NL + 255) / 256, 256, 0, stream>>>(pred, bl2);
  k_head<<<(NL / 32) * 2, 128, 0, stream>>>(hid, Wl1, bl1, Wl2, eli, pred);
}

// Round 9
// 583.420 us; speedup vs baseline: 1.0912x; 1.0912x over previous
//
#include <hip/hip_runtime.h>
#include <math.h>

// WinGNN forward on MI355X — f32 throughout (no fp32 MFMA on CDNA4).
//
// Pipeline (all on `stream`, graph-capture safe):
//  1. k_init      : deg=1 (self-loop), indeg=0
//  2. k_count     : atomic degree counts by row (norm) and col (CSR build)
//  3. k_scan      : single-block scan -> colptr/cursor; dinv=1/sqrt(deg)
//  4. k_fill      : CSR fill (csrc[pos] = row[e]) via atomic cursor
//  5. k_gemm<0>   : h = relu(x @ W1^T + b1)          [A-in-LDS + scalar-W GEMM]
//  6. k_agg<0>    : hn = A(h);  hidden = h + hn      [shuffle-broadcast gather]
//     k_agg<1>    : hidden += A(hn); then fused row-L2-normalize (no out store)
//  7. k_gemm<1>   : Z[v][0:128]=hid@Wl1[:,:128]^T, Z[v][128:256]=hid@Wl1[:,128:]^T
//                   (Z overlays dead h+hn buffers, 51.2MB)
//  8. k_edge      : pred[e] = b_l2 + sum_{o<128} Wl2[o]*relu(bl1[o]+Z[i][o]+Z[j][128+o])

#define NN 50000
#define NE 500000
#define NL 100000

__global__ __launch_bounds__(256) void k_init(int* __restrict__ deg,
                                              int* __restrict__ indeg) {
  int i = blockIdx.x * 256 + threadIdx.x;
  if (i < NN) { deg[i] = 1; indeg[i] = 0; }
}

__global__ __launch_bounds__(256) void k_count(const int* __restrict__ ei,
                                               int* __restrict__ deg,
                                               int* __restrict__ indeg) {
  int e = blockIdx.x * 256 + threadIdx.x;
  if (e < NE) {
    atomicAdd(&deg[ei[e]], 1);        // row -> deg (normalization)
    atomicAdd(&indeg[ei[NE + e]], 1); // col -> indeg (CSR)
  }
}

__global__ __launch_bounds__(1024) void k_scan(const int* __restrict__ indeg,
                                               const int* __restrict__ deg,
                                               float* __restrict__ dinv,
                                               int* __restrict__ colptr,
                                               int* __restrict__ cursor) {
  __shared__ int lds[1024];
  int tid = threadIdx.x;
  for (int i = tid; i < NN; i += 1024)
    dinv[i] = 1.0f / sqrtf((float)deg[i]);  // deg >= 1 always (self loop)

  const int C = (NN + 1023) / 1024;  // 49
  int base = tid * C;
  int sum = 0;
  for (int r = 0; r < C; ++r) {
    int idx = base + r;
    if (idx < NN) sum += indeg[idx];
  }
  lds[tid] = sum;
  __syncthreads();
  for (int s = 1; s < 1024; s <<= 1) {
    int v = (tid >= s) ? lds[tid - s] : 0;
    __syncthreads();
    lds[tid] += v;
    __syncthreads();
  }
  int run = lds[tid] - sum;  // exclusive prefix
  for (int r = 0; r < C; ++r) {
    int idx = base + r;
    if (idx < NN) {
      colptr[idx] = run;
      cursor[idx] = run;
      run += indeg[idx];
    }
  }
  if (tid == 1023) colptr[NN] = run;  // == NE
}

__global__ __launch_bounds__(256) void k_fill(const int* __restrict__ ei,
                                              int* __restrict__ cursor,
                                              int* __restrict__ csrc) {
  int e = blockIdx.x * 256 + threadIdx.x;
  if (e < NE) {
    int c = ei[NE + e];
    int pos = atomicAdd(&cursor[c], 1);
    csrc[pos] = ei[e];
  }
}

// ---------------- GEMM: C[M x NTOT] = act(A[M x 128] @ B^T (+ bias)) --------
// MODE 0: B row col = W1 + col*128,               relu+bias, NTOT=128
// MODE 1: B row col = Wl1 + (col&127)*256 + (col>>7)*128, plain, NTOT=256
// Block 256 thr (4 waves). Tile: 64 rows x 64 cols; wave w owns cols w*16..+15.
// A-tile transposed in LDS (AT[k][m], 32KB exactly -> 5 blocks/CU, 20 waves).
// lane = m-row; per k: 1 ds_read_b32 (2-way alias = free) + 16 FMA.
// nbase forced to SGPR via readfirstlane -> W loads become s_load_dwordx4
// (SMEM pipe, immediate offsets), keeping VMEM/L1 free for the A staging.
template <int MODE, int NTOT>
__global__ __launch_bounds__(256) void k_gemm(const float* __restrict__ A,
                                              const float* __restrict__ W,
                                              const float* __restrict__ bias,
                                              float* __restrict__ C) {
  __shared__ float AT[128][64];
  int t = threadIdx.x;
  int m0 = blockIdx.x * 64;
  {
    int r = t & 63, kq = t >> 6;  // kq in 0..3 -> k chunk of 32
    bool valid = (m0 + r) < NN;
    const float* arow = A + (size_t)(m0 + r) * 128 + kq * 32;
#pragma unroll
    for (int j = 0; j < 8; ++j) {
      float4 v = valid ? *(const float4*)(arow + j * 4) : make_float4(0.f, 0.f, 0.f, 0.f);
      int k = kq * 32 + j * 4;
      AT[k + 0][r] = v.x;  // lanes sweep r -> consecutive banks, conflict-free
      AT[k + 1][r] = v.y;
      AT[k + 2][r] = v.z;
      AT[k + 3][r] = v.w;
    }
  }
  __syncthreads();

  int lane = t & 63, w = t >> 6;
  // wave-uniform in fact; readfirstlane makes it provably uniform -> s_load path
  int nbase = __builtin_amdgcn_readfirstlane(blockIdx.y * 64 + w * 16);
  float acc[16] = {};
  for (int k4 = 0; k4 < 32; ++k4) {
    int k = k4 * 4;
    float a0 = AT[k + 0][lane];
    float a1 = AT[k + 1][lane];
    float a2 = AT[k + 2][lane];
    float a3 = AT[k + 3][lane];
#pragma unroll
    for (int n = 0; n < 16; ++n) {
      int col = nbase + n;
      const float* bp = (MODE == 0)
                            ? (W + col * 128 + k)
                            : (W + (col & 127) * 256 + ((col >> 7) << 7) + k);
      float4 b = *(const float4*)bp;  // uniform -> scalar load
      acc[n] += a0 * b.x;
      acc[n] += a1 * b.y;
      acc[n] += a2 * b.z;
      acc[n] += a3 * b.w;
    }
  }

  int m = m0 + lane;
  if (m < NN) {
    float* crow = C + (size_t)m * NTOT + nbase;
#pragma unroll
    for (int n4 = 0; n4 < 4; ++n4) {
      float4 o;
      if (MODE == 0) {
        float4 bb = *(const float4*)(bias + nbase + n4 * 4);
        o.x = fmaxf(acc[n4 * 4 + 0] + bb.x, 0.f);
        o.y = fmaxf(acc[n4 * 4 + 1] + bb.y, 0.f);
        o.z = fmaxf(acc[n4 * 4 + 2] + bb.z, 0.f);
        o.w = fmaxf(acc[n4 * 4 + 3] + bb.w, 0.f);
      } else {
        o.x = acc[n4 * 4 + 0];
        o.y = acc[n4 * 4 + 1];
        o.z = acc[n4 * 4 + 2];
        o.w = acc[n4 * 4 + 3];
      }
      *(float4*)(crow + n4 * 4) = o;
    }
  }
}

// ---------------- aggregation hop ----------------
// half-wave (32 lanes x float4) per node:
// agg = dinv[v] * ( sum_in dinv[src]*in[src] + dinv[v]*in[v] )
// Edge indices + dinv are prefetched 32-at-a-time cooperatively (one coalesced
// load per chunk) and broadcast via width-32 shuffles; feature gathers are
// 2-way unrolled so two independent loads are in flight (latency, not BW,
// is the bottleneck). Trip counts are half-wave-uniform -> no divergence.
// LAST=0: out = agg; hidden = in[v] + agg
// LAST=1: hidden += agg, then fused row-L2-normalize (no out store)
template <int LAST>
__global__ __launch_bounds__(256) void k_agg(const float* __restrict__ in,
                                             float* __restrict__ out,
                                             float* __restrict__ hidden,
                                             const float* __restrict__ dinv,
                                             const int* __restrict__ colptr,
                                             const int* __restrict__ csrc) {
  int v = (blockIdx.x * 256 + threadIdx.x) >> 5;
  int l = threadIdx.x & 31;
  if (v >= NN) return;
  float dv = dinv[v];
  float4 sv = *(const float4*)(in + (size_t)v * 128 + l * 4);
  float ax = sv.x * dv, ay = sv.y * dv, az = sv.z * dv, aw = sv.w * dv;
  int s = colptr[v], e = colptr[v + 1];
  for (int p0 = s; p0 < e; p0 += 32) {
    int cnt = e - p0;
    if (cnt > 32) cnt = 32;
    int myi = (l < cnt) ? csrc[p0 + l] : 0;     // coalesced 128B index load
    float myd = (l < cnt) ? dinv[myi] : 0.0f;   // one dinv gather per edge
    int q = 0;
    for (; q + 1 < cnt; q += 2) {
      int s0 = __shfl(myi, q, 32);
      int s1 = __shfl(myi, q + 1, 32);
      float d0 = __shfl(myd, q, 32);
      float d1 = __shfl(myd, q + 1, 32);
      float4 h0 = *(const float4*)(in + (size_t)s0 * 128 + l * 4);
      float4 h1 = *(const float4*)(in + (size_t)s1 * 128 + l * 4);
      ax += h0.x * d0 + h1.x * d1;
      ay += h0.y * d0 + h1.y * d1;
      az += h0.z * d0 + h1.z * d1;
      aw += h0.w * d0 + h1.w * d1;
    }
    if (q < cnt) {
      int s0 = __shfl(myi, q, 32);
      float d0 = __shfl(myd, q, 32);
      float4 h0 = *(const float4*)(in + (size_t)s0 * 128 + l * 4);
      ax += h0.x * d0;
      ay += h0.y * d0;
      az += h0.z * d0;
      aw += h0.w * d0;
    }
  }
  ax *= dv; ay *= dv; az *= dv; aw *= dv;
  if (!LAST) {
    float4 o4 = {ax, ay, az, aw};
    *(float4*)(out + (size_t)v * 128 + l * 4) = o4;
    float4 hd = {sv.x + ax, sv.y + ay, sv.z + az, sv.w + aw};
    *(float4*)(hidden + (size_t)v * 128 + l * 4) = hd;
  } else {
    float4 hp = *(const float4*)(hidden + (size_t)v * 128 + l * 4);
    float4 hd = {hp.x + ax, hp.y + ay, hp.z + az, hp.w + aw};
    // fused F.normalize: half-wave owns the whole 128-dim row
    float ss = hd.x * hd.x + hd.y * hd.y + hd.z * hd.z + hd.w * hd.w;
#pragma unroll
    for (int d = 1; d < 32; d <<= 1) ss += __shfl_xor(ss, d, 64);  // masks 1..16
    float sc = 1.0f / fmaxf(sqrtf(ss), 1e-12f);
    float4 r = {hd.x * sc, hd.y * sc, hd.z * sc, hd.w * sc};
    *(float4*)(hidden + (size_t)v * 128 + l * 4) = r;
  }
}

// ---------------- edge head reduce ----------------
// 16 lanes per edge, each lane covers o = l*4..+3 and o = 64+l*4..+3:
// pred[e] = b_l2 + sum_{o<128} Wl2[o]*relu(bl1[o]+Z[i][o]+Z[j][128+o])
__global__ __launch_bounds__(256) void k_edge(const float* __restrict__ Z,
                                              const float* __restrict__ bl1,
                                              const float* __restrict__ Wl2,
                                              const float* __restrict__ bl2,
                                              const int* __restrict__ eli,
                                              float* __restrict__ pred) {
  int g = blockIdx.x * 256 + threadIdx.x;
  int e = g >> 4;
  int l = g & 15;
  if (e >= NL) return;
  int i = eli[e], j = eli[NL + e];
  const float* zi = Z + (size_t)i * 256;
  const float* zj = Z + (size_t)j * 256 + 128;
  float s = 0.0f;
#pragma unroll
  for (int half = 0; half < 2; ++half) {
    int o = half * 64 + l * 4;
    float4 za = *(const float4*)(zi + o);
    float4 zb = *(const float4*)(zj + o);
    float4 bb = *(const float4*)(bl1 + o);
    float4 w2 = *(const float4*)(Wl2 + o);
    s += fmaxf(za.x + zb.x + bb.x, 0.f) * w2.x
       + fmaxf(za.y + zb.y + bb.y, 0.f) * w2.y
       + fmaxf(za.z + zb.z + bb.z, 0.f) * w2.z
       + fmaxf(za.w + zb.w + bb.w, 0.f) * w2.w;
  }
#pragma unroll
  for (int d = 1; d < 16; d <<= 1) s += __shfl_xor(s, d, 64);
  if (l == 0) pred[e] = s + bl2[0];
}

extern "C" void kernel_launch(void* const* d_in, const int* in_sizes, int n_in,
                              void* d_out, int out_size, void* d_ws, size_t ws_size,
                              hipStream_t stream) {
  const float* x   = (const float*)d_in[0];
  const float* W1  = (const float*)d_in[1];
  const float* b1  = (const float*)d_in[2];
  const float* Wl1 = (const float*)d_in[3];
  const float* bl1 = (const float*)d_in[4];
  const float* Wl2 = (const float*)d_in[5];
  const float* bl2 = (const float*)d_in[6];
  const int* ei    = (const int*)d_in[7];
  const int* eli   = (const int*)d_in[8];
  float* pred = (float*)d_out;

  char* ws = (char*)d_ws;
  size_t off = 0;
  auto alloc = [&](size_t bytes) {
    void* p = ws + off;
    off = (off + bytes + 255) & ~(size_t)255;
    return p;
  };
  float* dinv  = (float*)alloc(NN * 4);
  int* deg     = (int*)alloc(NN * 4);
  int* indeg   = (int*)alloc(NN * 4);
  int* colptr  = (int*)alloc((NN + 1) * 4);
  int* cursor  = (int*)alloc(NN * 4);
  int* csrc    = (int*)alloc((size_t)NE * 4);
  float* h     = (float*)alloc((size_t)NN * 128 * 4);
  float* hn    = (float*)alloc((size_t)NN * 128 * 4);  // contiguous after h
  float* hid   = (float*)alloc((size_t)NN * 128 * 4);
  float* Z     = h;  // 50000x256 f32 = 51.2MB overlays dead h+hn after agg

  k_init<<<(NN + 255) / 256, 256, 0, stream>>>(deg, indeg);
  k_count<<<(NE + 255) / 256, 256, 0, stream>>>(ei, deg, indeg);
  k_scan<<<1, 1024, 0, stream>>>(indeg, deg, dinv, colptr, cursor);
  k_fill<<<(NE + 255) / 256, 256, 0, stream>>>(ei, cursor, csrc);

  const int MB = (NN + 63) / 64;  // 782
  k_gemm<0, 128><<<dim3(MB, 2), 256, 0, stream>>>(x, W1, b1, h);

  k_agg<0><<<(NN * 32 + 255) / 256, 256, 0, stream>>>(h, hn, hid, dinv, colptr, csrc);
  k_agg<1><<<(NN * 32 + 255) / 256, 256, 0, stream>>>(hn, nullptr, hid, dinv, colptr, csrc);

  k_gemm<1, 256><<<dim3(MB, 4), 256, 0, stream>>>(hid, Wl1, nullptr, Z);

  k_edge<<<(NL * 16 + 255) / 256, 256, 0, stream>>>(Z, bl1, Wl2, bl2, eli, pred);
}

// Round 10
// 458.272 us; speedup vs baseline: 1.3892x; 1.2731x over previous
//
#include <hip/hip_runtime.h>
#include <math.h>

// WinGNN forward on MI355X — f32 throughout (no fp32 MFMA on CDNA4).
//
// Pipeline (all on `stream`, graph-capture safe):
//  1. k_init        : deg=1 (self-loop), indeg=0
//  2. k_count       : atomic degree counts by row (norm) and col (CSR build)
//  3. k_blocksum    : per-256-chunk sum of indeg -> bsum ; dinv=rsqrt(deg)   [coalesced]
//     k_scan_bsums  : 1-block exclusive scan of 196 bsums -> boff            [tiny]
//     k_colptr      : per-chunk LDS scan + boff -> colptr/cursor             [coalesced]
//  4. k_fill        : CSR fill (csrc[pos] = row[e]) via atomic cursor
//  5. k_gemm<0>     : h = relu(x @ W1^T + b1)          [A-in-LDS + scalar-W GEMM]
//  6. k_agg<0>      : hn = A(h);  hidden = h + hn      [shuffle-broadcast gather]
//     k_agg<1>      : hidden += A(hn); then fused row-L2-normalize
//  7. k_gemm<1>     : Z[v][0:128]=hid@Wl1[:,:128]^T, Z[v][128:256]=hid@Wl1[:,128:]^T
//  8. k_edge        : pred[e] = b_l2 + sum_{o<128} Wl2[o]*relu(bl1[o]+Z[i][o]+Z[j][128+o])

#define NN 50000
#define NE 500000
#define NL 100000
#define NB 196  // ceil(NN/256)

__global__ __launch_bounds__(256) void k_init(int* __restrict__ deg,
                                              int* __restrict__ indeg) {
  int i = blockIdx.x * 256 + threadIdx.x;
  if (i < NN) { deg[i] = 1; indeg[i] = 0; }
}

__global__ __launch_bounds__(256) void k_count(const int* __restrict__ ei,
                                               int* __restrict__ deg,
                                               int* __restrict__ indeg) {
  int e = blockIdx.x * 256 + threadIdx.x;
  if (e < NE) {
    atomicAdd(&deg[ei[e]], 1);        // row -> deg (normalization)
    atomicAdd(&indeg[ei[NE + e]], 1); // col -> indeg (CSR)
  }
}

// ---- hierarchical scan stage 1: block sums (coalesced) + dinv ----
__global__ __launch_bounds__(256) void k_blocksum(const int* __restrict__ indeg,
                                                  const int* __restrict__ deg,
                                                  float* __restrict__ dinv,
                                                  int* __restrict__ bsum) {
  __shared__ int red[4];
  int t = threadIdx.x;
  int i = blockIdx.x * 256 + t;
  int v = (i < NN) ? indeg[i] : 0;
  if (i < NN) dinv[i] = 1.0f / sqrtf((float)deg[i]);  // deg >= 1 (self loop)
  int sum = v;
#pragma unroll
  for (int d = 1; d < 64; d <<= 1) sum += __shfl_xor(sum, d, 64);
  if ((t & 63) == 0) red[t >> 6] = sum;
  __syncthreads();
  if (t == 0) bsum[blockIdx.x] = red[0] + red[1] + red[2] + red[3];
}

// ---- stage 2: exclusive scan of NB block sums (single tiny block) ----
__global__ __launch_bounds__(256) void k_scan_bsums(const int* __restrict__ bsum,
                                                    int* __restrict__ boff) {
  __shared__ int s[256];
  int t = threadIdx.x;
  int v = (t < NB) ? bsum[t] : 0;
  s[t] = v;
  __syncthreads();
  for (int d = 1; d < 256; d <<= 1) {
    int u = (t >= d) ? s[t - d] : 0;
    __syncthreads();
    s[t] += u;
    __syncthreads();
  }
  if (t < NB) boff[t] = s[t] - v;  // exclusive prefix
}

// ---- stage 3: per-block scan + offset -> colptr/cursor (coalesced) ----
__global__ __launch_bounds__(256) void k_colptr(const int* __restrict__ indeg,
                                                const int* __restrict__ boff,
                                                int* __restrict__ colptr,
                                                int* __restrict__ cursor) {
  __shared__ int s[256];
  int t = threadIdx.x;
  int i = blockIdx.x * 256 + t;
  int v = (i < NN) ? indeg[i] : 0;
  s[t] = v;
  __syncthreads();
  for (int d = 1; d < 256; d <<= 1) {
    int u = (t >= d) ? s[t - d] : 0;
    __syncthreads();
    s[t] += u;
    __syncthreads();
  }
  int incl = s[t];
  int base = boff[blockIdx.x];
  if (i < NN) {
    int ex = base + incl - v;
    colptr[i] = ex;
    cursor[i] = ex;
    if (i == NN - 1) colptr[NN] = base + incl;  // == NE
  }
}

__global__ __launch_bounds__(256) void k_fill(const int* __restrict__ ei,
                                              int* __restrict__ cursor,
                                              int* __restrict__ csrc) {
  int e = blockIdx.x * 256 + threadIdx.x;
  if (e < NE) {
    int c = ei[NE + e];
    int pos = atomicAdd(&cursor[c], 1);
    csrc[pos] = ei[e];
  }
}

// ---------------- GEMM: C[M x NTOT] = act(A[M x 128] @ B^T (+ bias)) --------
// MODE 0: B row col = W1 + col*128,               relu+bias, NTOT=128
// MODE 1: B row col = Wl1 + (col&127)*256 + (col>>7)*128, plain, NTOT=256
// Block 256 thr (4 waves). Tile: 64 rows x 64 cols; wave w owns cols w*16..+15.
// A-tile transposed in LDS (AT[k][m], 32KB exactly -> 5 blocks/CU, 20 waves).
// lane = m-row; per k: 1 ds_read_b32 (2-way alias = free) + 16 FMA.
// nbase forced to SGPR via readfirstlane -> W loads become s_load_dwordx4.
template <int MODE, int NTOT>
__global__ __launch_bounds__(256) void k_gemm(const float* __restrict__ A,
                                              const float* __restrict__ W,
                                              const float* __restrict__ bias,
                                              float* __restrict__ C) {
  __shared__ float AT[128][64];
  int t = threadIdx.x;
  int m0 = blockIdx.x * 64;
  {
    int r = t & 63, kq = t >> 6;  // kq in 0..3 -> k chunk of 32
    bool valid = (m0 + r) < NN;
    const float* arow = A + (size_t)(m0 + r) * 128 + kq * 32;
#pragma unroll
    for (int j = 0; j < 8; ++j) {
      float4 v = valid ? *(const float4*)(arow + j * 4) : make_float4(0.f, 0.f, 0.f, 0.f);
      int k = kq * 32 + j * 4;
      AT[k + 0][r] = v.x;  // lanes sweep r -> consecutive banks, conflict-free
      AT[k + 1][r] = v.y;
      AT[k + 2][r] = v.z;
      AT[k + 3][r] = v.w;
    }
  }
  __syncthreads();

  int lane = t & 63, w = t >> 6;
  // wave-uniform in fact; readfirstlane makes it provably uniform -> s_load path
  int nbase = __builtin_amdgcn_readfirstlane(blockIdx.y * 64 + w * 16);
  float acc[16] = {};
  for (int k4 = 0; k4 < 32; ++k4) {
    int k = k4 * 4;
    float a0 = AT[k + 0][lane];
    float a1 = AT[k + 1][lane];
    float a2 = AT[k + 2][lane];
    float a3 = AT[k + 3][lane];
#pragma unroll
    for (int n = 0; n < 16; ++n) {
      int col = nbase + n;
      const float* bp = (MODE == 0)
                            ? (W + col * 128 + k)
                            : (W + (col & 127) * 256 + ((col >> 7) << 7) + k);
      float4 b = *(const float4*)bp;  // uniform -> scalar load
      acc[n] += a0 * b.x;
      acc[n] += a1 * b.y;
      acc[n] += a2 * b.z;
      acc[n] += a3 * b.w;
    }
  }

  int m = m0 + lane;
  if (m < NN) {
    float* crow = C + (size_t)m * NTOT + nbase;
#pragma unroll
    for (int n4 = 0; n4 < 4; ++n4) {
      float4 o;
      if (MODE == 0) {
        float4 bb = *(const float4*)(bias + nbase + n4 * 4);
        o.x = fmaxf(acc[n4 * 4 + 0] + bb.x, 0.f);
        o.y = fmaxf(acc[n4 * 4 + 1] + bb.y, 0.f);
        o.z = fmaxf(acc[n4 * 4 + 2] + bb.z, 0.f);
        o.w = fmaxf(acc[n4 * 4 + 3] + bb.w, 0.f);
      } else {
        o.x = acc[n4 * 4 + 0];
        o.y = acc[n4 * 4 + 1];
        o.z = acc[n4 * 4 + 2];
        o.w = acc[n4 * 4 + 3];
      }
      *(float4*)(crow + n4 * 4) = o;
    }
  }
}

// ---------------- aggregation hop ----------------
// half-wave (32 lanes x float4) per node:
// agg = dinv[v] * ( sum_in dinv[src]*in[src] + dinv[v]*in[v] )
// Edge indices + dinv prefetched 32-at-a-time cooperatively (coalesced) and
// broadcast via width-32 shuffles; feature gathers 2-way unrolled.
// LAST=0: out = agg; hidden = in[v] + agg
// LAST=1: hidden += agg, then fused row-L2-normalize (no out store)
template <int LAST>
__global__ __launch_bounds__(256) void k_agg(const float* __restrict__ in,
                                             float* __restrict__ out,
                                             float* __restrict__ hidden,
                                             const float* __restrict__ dinv,
                                             const int* __restrict__ colptr,
                                             const int* __restrict__ csrc) {
  int v = (blockIdx.x * 256 + threadIdx.x) >> 5;
  int l = threadIdx.x & 31;
  if (v >= NN) return;
  float dv = dinv[v];
  float4 sv = *(const float4*)(in + (size_t)v * 128 + l * 4);
  float ax = sv.x * dv, ay = sv.y * dv, az = sv.z * dv, aw = sv.w * dv;
  int s = colptr[v], e = colptr[v + 1];
  for (int p0 = s; p0 < e; p0 += 32) {
    int cnt = e - p0;
    if (cnt > 32) cnt = 32;
    int myi = (l < cnt) ? csrc[p0 + l] : 0;     // coalesced 128B index load
    float myd = (l < cnt) ? dinv[myi] : 0.0f;   // one dinv gather per edge
    int q = 0;
    for (; q + 1 < cnt; q += 2) {
      int s0 = __shfl(myi, q, 32);
      int s1 = __shfl(myi, q + 1, 32);
      float d0 = __shfl(myd, q, 32);
      float d1 = __shfl(myd, q + 1, 32);
      float4 h0 = *(const float4*)(in + (size_t)s0 * 128 + l * 4);
      float4 h1 = *(const float4*)(in + (size_t)s1 * 128 + l * 4);
      ax += h0.x * d0 + h1.x * d1;
      ay += h0.y * d0 + h1.y * d1;
      az += h0.z * d0 + h1.z * d1;
      aw += h0.w * d0 + h1.w * d1;
    }
    if (q < cnt) {
      int s0 = __shfl(myi, q, 32);
      float d0 = __shfl(myd, q, 32);
      float4 h0 = *(const float4*)(in + (size_t)s0 * 128 + l * 4);
      ax += h0.x * d0;
      ay += h0.y * d0;
      az += h0.z * d0;
      aw += h0.w * d0;
    }
  }
  ax *= dv; ay *= dv; az *= dv; aw *= dv;
  if (!LAST) {
    float4 o4 = {ax, ay, az, aw};
    *(float4*)(out + (size_t)v * 128 + l * 4) = o4;
    float4 hd = {sv.x + ax, sv.y + ay, sv.z + az, sv.w + aw};
    *(float4*)(hidden + (size_t)v * 128 + l * 4) = hd;
  } else {
    float4 hp = *(const float4*)(hidden + (size_t)v * 128 + l * 4);
    float4 hd = {hp.x + ax, hp.y + ay, hp.z + az, hp.w + aw};
    // fused F.normalize: half-wave owns the whole 128-dim row
    float ss = hd.x * hd.x + hd.y * hd.y + hd.z * hd.z + hd.w * hd.w;
#pragma unroll
    for (int d = 1; d < 32; d <<= 1) ss += __shfl_xor(ss, d, 64);  // masks 1..16
    float sc = 1.0f / fmaxf(sqrtf(ss), 1e-12f);
    float4 r = {hd.x * sc, hd.y * sc, hd.z * sc, hd.w * sc};
    *(float4*)(hidden + (size_t)v * 128 + l * 4) = r;
  }
}

// ---------------- edge head reduce ----------------
// 16 lanes per edge, each lane covers o = l*4..+3 and o = 64+l*4..+3:
// pred[e] = b_l2 + sum_{o<128} Wl2[o]*relu(bl1[o]+Z[i][o]+Z[j][128+o])
__global__ __launch_bounds__(256) void k_edge(const float* __restrict__ Z,
                                              const float* __restrict__ bl1,
                                              const float* __restrict__ Wl2,
                                              const float* __restrict__ bl2,
                                              const int* __restrict__ eli,
                                              float* __restrict__ pred) {
  int g = blockIdx.x * 256 + threadIdx.x;
  int e = g >> 4;
  int l = g & 15;
  if (e >= NL) return;
  int i = eli[e], j = eli[NL + e];
  const float* zi = Z + (size_t)i * 256;
  const float* zj = Z + (size_t)j * 256 + 128;
  float s = 0.0f;
#pragma unroll
  for (int half = 0; half < 2; ++half) {
    int o = half * 64 + l * 4;
    float4 za = *(const float4*)(zi + o);
    float4 zb = *(const float4*)(zj + o);
    float4 bb = *(const float4*)(bl1 + o);
    float4 w2 = *(const float4*)(Wl2 + o);
    s += fmaxf(za.x + zb.x + bb.x, 0.f) * w2.x
       + fmaxf(za.y + zb.y + bb.y, 0.f) * w2.y
       + fmaxf(za.z + zb.z + bb.z, 0.f) * w2.z
       + fmaxf(za.w + zb.w + bb.w, 0.f) * w2.w;
  }
#pragma unroll
  for (int d = 1; d < 16; d <<= 1) s += __shfl_xor(s, d, 64);
  if (l == 0) pred[e] = s + bl2[0];
}

extern "C" void kernel_launch(void* const* d_in, const int* in_sizes, int n_in,
                              void* d_out, int out_size, void* d_ws, size_t ws_size,
                              hipStream_t stream) {
  const float* x   = (const float*)d_in[0];
  const float* W1  = (const float*)d_in[1];
  const float* b1  = (const float*)d_in[2];
  const float* Wl1 = (const float*)d_in[3];
  const float* bl1 = (const float*)d_in[4];
  const float* Wl2 = (const float*)d_in[5];
  const float* bl2 = (const float*)d_in[6];
  const int* ei    = (const int*)d_in[7];
  const int* eli   = (const int*)d_in[8];
  float* pred = (float*)d_out;

  char* ws = (char*)d_ws;
  size_t off = 0;
  auto alloc = [&](size_t bytes) {
    void* p = ws + off;
    off = (off + bytes + 255) & ~(size_t)255;
    return p;
  };
  float* dinv  = (float*)alloc(NN * 4);
  int* deg     = (int*)alloc(NN * 4);
  int* indeg   = (int*)alloc(NN * 4);
  int* colptr  = (int*)alloc((NN + 1) * 4);
  int* cursor  = (int*)alloc(NN * 4);
  int* bsum    = (int*)alloc(NB * 4);
  int* boff    = (int*)alloc(NB * 4);
  int* csrc    = (int*)alloc((size_t)NE * 4);
  float* h     = (float*)alloc((size_t)NN * 128 * 4);
  float* hn    = (float*)alloc((size_t)NN * 128 * 4);  // contiguous after h
  float* hid   = (float*)alloc((size_t)NN * 128 * 4);
  float* Z     = h;  // 50000x256 f32 = 51.2MB overlays dead h+hn after agg

  k_init<<<NB, 256, 0, stream>>>(deg, indeg);
  k_count<<<(NE + 255) / 256, 256, 0, stream>>>(ei, deg, indeg);
  k_blocksum<<<NB, 256, 0, stream>>>(indeg, deg, dinv, bsum);
  k_scan_bsums<<<1, 256, 0, stream>>>(bsum, boff);
  k_colptr<<<NB, 256, 0, stream>>>(indeg, boff, colptr, cursor);
  k_fill<<<(NE + 255) / 256, 256, 0, stream>>>(ei, cursor, csrc);

  const int MB = (NN + 63) / 64;  // 782
  k_gemm<0, 128><<<dim3(MB, 2), 256, 0, stream>>>(x, W1, b1, h);

  k_agg<0><<<(NN * 32 + 255) / 256, 256, 0, stream>>>(h, hn, hid, dinv, colptr, csrc);
  k_agg<1><<<(NN * 32 + 255) / 256, 256, 0, stream>>>(hn, nullptr, hid, dinv, colptr, csrc);

  k_gemm<1, 256><<<dim3(MB, 4), 256, 0, stream>>>(hid, Wl1, nullptr, Z);

  k_edge<<<(NL * 16 + 255) / 256, 256, 0, stream>>>(Z, bl1, Wl2, bl2, eli, pred);
}

// Round 11
// 347.589 us; speedup vs baseline: 1.8315x; 1.3184x over previous
//
#include <hip/hip_runtime.h>
#include <math.h>

// WinGNN forward on MI355X — f32 throughout (no fp32 MFMA on CDNA4).
//
// Pipeline (all on `stream`, graph-capture safe):
//  1. k_init        : deg=1 (self-loop), indeg=0
//  2. k_count       : atomic degree counts by row (norm) and col (CSR build)
//  3. k_blocksum    : per-256-chunk sum of indeg -> bsum ; dinv=rsqrt(deg)
//     k_scan_bsums  : 1-block exclusive scan of 196 bsums -> boff
//     k_colptr      : per-chunk LDS scan + boff -> colptr/cursor
//  4. k_fill        : CSR fill (csrc[pos] = row[e]) via atomic cursor
//  5. k_transW      : WT1[k][n]=W1[n][k]; WTl1[k][n]=Wl1 concat-transposed
//  6. k_gemm_h      : h = relu(x @ W1^T + b1)    [lane=col, scalar-A, no LDS]
//  7. k_agg<0>      : hn = A(h);  hidden = h + hn  [shuffle-broadcast gather]
//     k_agg<1>      : hidden += A(hn); fused row-L2-normalize
//  8. k_gemm_z      : Z[v][n] = hid @ WTl1        [same structure, 256 cols]
//  9. k_edge        : pred[e] = b_l2 + sum_o Wl2[o]*relu(bl1[o]+Z[i][o]+Z[j][128+o])

#define NN 50000
#define NE 500000
#define NL 100000
#define NB 196  // ceil(NN/256)

__global__ __launch_bounds__(256) void k_init(int* __restrict__ deg,
                                              int* __restrict__ indeg) {
  int i = blockIdx.x * 256 + threadIdx.x;
  if (i < NN) { deg[i] = 1; indeg[i] = 0; }
}

__global__ __launch_bounds__(256) void k_count(const int* __restrict__ ei,
                                               int* __restrict__ deg,
                                               int* __restrict__ indeg) {
  int e = blockIdx.x * 256 + threadIdx.x;
  if (e < NE) {
    atomicAdd(&deg[ei[e]], 1);        // row -> deg (normalization)
    atomicAdd(&indeg[ei[NE + e]], 1); // col -> indeg (CSR)
  }
}

// ---- hierarchical scan stage 1: block sums (coalesced) + dinv ----
__global__ __launch_bounds__(256) void k_blocksum(const int* __restrict__ indeg,
                                                  const int* __restrict__ deg,
                                                  float* __restrict__ dinv,
                                                  int* __restrict__ bsum) {
  __shared__ int red[4];
  int t = threadIdx.x;
  int i = blockIdx.x * 256 + t;
  int v = (i < NN) ? indeg[i] : 0;
  if (i < NN) dinv[i] = 1.0f / sqrtf((float)deg[i]);  // deg >= 1 (self loop)
  int sum = v;
#pragma unroll
  for (int d = 1; d < 64; d <<= 1) sum += __shfl_xor(sum, d, 64);
  if ((t & 63) == 0) red[t >> 6] = sum;
  __syncthreads();
  if (t == 0) bsum[blockIdx.x] = red[0] + red[1] + red[2] + red[3];
}

// ---- stage 2: exclusive scan of NB block sums (single tiny block) ----
__global__ __launch_bounds__(256) void k_scan_bsums(const int* __restrict__ bsum,
                                                    int* __restrict__ boff) {
  __shared__ int s[256];
  int t = threadIdx.x;
  int v = (t < NB) ? bsum[t] : 0;
  s[t] = v;
  __syncthreads();
  for (int d = 1; d < 256; d <<= 1) {
    int u = (t >= d) ? s[t - d] : 0;
    __syncthreads();
    s[t] += u;
    __syncthreads();
  }
  if (t < NB) boff[t] = s[t] - v;  // exclusive prefix
}

// ---- stage 3: per-block scan + offset -> colptr/cursor (coalesced) ----
__global__ __launch_bounds__(256) void k_colptr(const int* __restrict__ indeg,
                                                const int* __restrict__ boff,
                                                int* __restrict__ colptr,
                                                int* __restrict__ cursor) {
  __shared__ int s[256];
  int t = threadIdx.x;
  int i = blockIdx.x * 256 + t;
  int v = (i < NN) ? indeg[i] : 0;
  s[t] = v;
  __syncthreads();
  for (int d = 1; d < 256; d <<= 1) {
    int u = (t >= d) ? s[t - d] : 0;
    __syncthreads();
    s[t] += u;
    __syncthreads();
  }
  int incl = s[t];
  int base = boff[blockIdx.x];
  if (i < NN) {
    int ex = base + incl - v;
    colptr[i] = ex;
    cursor[i] = ex;
    if (i == NN - 1) colptr[NN] = base + incl;  // == NE
  }
}

__global__ __launch_bounds__(256) void k_fill(const int* __restrict__ ei,
                                              int* __restrict__ cursor,
                                              int* __restrict__ csrc) {
  int e = blockIdx.x * 256 + threadIdx.x;
  if (e < NE) {
    int c = ei[NE + e];
    int pos = atomicAdd(&cursor[c], 1);
    csrc[pos] = ei[e];
  }
}

// ---- weight transpose (one-time, ~192KB): WT[k][n] layouts ----
// WT1 [128][128]: WT1[k*128+n]  = W1[n*128+k]
// WTl1[128][256]: WTl1[k*256+n] = (n<128) ? Wl1[n*256+k] : Wl1[(n-128)*256+128+k]
__global__ __launch_bounds__(256) void k_transW(const float* __restrict__ W1,
                                                const float* __restrict__ Wl1,
                                                float* __restrict__ WT1,
                                                float* __restrict__ WTl1) {
  int i = blockIdx.x * 256 + threadIdx.x;
  if (i < 128 * 128) {
    int k = i >> 7, n = i & 127;
    WT1[i] = W1[n * 128 + k];
  } else {
    int i2 = i - 128 * 128;
    if (i2 < 128 * 256) {
      int k = i2 >> 8, n = i2 & 255;
      WTl1[i2] = (n < 128) ? Wl1[n * 256 + k] : Wl1[(n - 128) * 256 + 128 + k];
    }
  }
}

// ---------------- GEMM h: h = relu(x @ W1^T + b1) ----------------
// lane = column (2 cols via float2), wave = 8 rows x 128 cols, block = 32 rows.
// A-side wave-uniform -> s_load_dwordx4 (8/chunk); W-side coalesced
// global_load_dwordx2 from WT1 (L2-resident, shared across waves);
// C-stores coalesced (lane-consecutive cols). No LDS -> occupancy VGPR-only.
__global__ __launch_bounds__(256) void k_gemm_h(const float* __restrict__ A,
                                                const float* __restrict__ WT,
                                                const float* __restrict__ bias,
                                                float* __restrict__ C) {
  int t = threadIdx.x;
  int lane = t & 63;
  int w = __builtin_amdgcn_readfirstlane(t >> 6);
  int m0 = blockIdx.x * 32 + w * 8;
  int c0 = lane * 2;
  float2 acc[8];
#pragma unroll
  for (int r = 0; r < 8; ++r) acc[r] = make_float2(0.f, 0.f);
  const float* arow[8];
#pragma unroll
  for (int r = 0; r < 8; ++r) {
    int m = m0 + r;
    if (m > NN - 1) m = NN - 1;  // clamp: OOB rows read valid mem, store guarded
    arow[r] = A + (size_t)m * 128;
  }
  for (int k0 = 0; k0 < 128; k0 += 4) {
    float4 a[8];
#pragma unroll
    for (int r = 0; r < 8; ++r) a[r] = *(const float4*)(arow[r] + k0);  // s_load
#pragma unroll
    for (int kk = 0; kk < 4; ++kk) {
      float2 wv = *(const float2*)(WT + (size_t)(k0 + kk) * 128 + c0);  // coalesced
#pragma unroll
      for (int r = 0; r < 8; ++r) {
        float ar = (kk == 0) ? a[r].x : (kk == 1) ? a[r].y : (kk == 2) ? a[r].z : a[r].w;
        acc[r].x += ar * wv.x;
        acc[r].y += ar * wv.y;
      }
    }
  }
  float2 bb = *(const float2*)(bias + c0);
#pragma unroll
  for (int r = 0; r < 8; ++r) {
    int m = m0 + r;
    if (m < NN) {
      float2 o;
      o.x = fmaxf(acc[r].x + bb.x, 0.f);
      o.y = fmaxf(acc[r].y + bb.y, 0.f);
      *(float2*)(C + (size_t)m * 128 + c0) = o;  // lane-consecutive: coalesced
    }
  }
}

// ---------------- GEMM z: Z = hid @ WTl1 (256 cols) ----------------
// lane = column (4 cols via float4), wave = 8 rows x 256 cols, block = 32 rows.
__global__ __launch_bounds__(256) void k_gemm_z(const float* __restrict__ A,
                                                const float* __restrict__ WT,
                                                float* __restrict__ Z) {
  int t = threadIdx.x;
  int lane = t & 63;
  int w = __builtin_amdgcn_readfirstlane(t >> 6);
  int m0 = blockIdx.x * 32 + w * 8;
  int c0 = lane * 4;
  float4 acc[8];
#pragma unroll
  for (int r = 0; r < 8; ++r) acc[r] = make_float4(0.f, 0.f, 0.f, 0.f);
  const float* arow[8];
#pragma unroll
  for (int r = 0; r < 8; ++r) {
    int m = m0 + r;
    if (m > NN - 1) m = NN - 1;
    arow[r] = A + (size_t)m * 128;
  }
  for (int k0 = 0; k0 < 128; k0 += 4) {
    float4 a[8];
#pragma unroll
    for (int r = 0; r < 8; ++r) a[r] = *(const float4*)(arow[r] + k0);  // s_load
#pragma unroll
    for (int kk = 0; kk < 4; ++kk) {
      float4 wv = *(const float4*)(WT + (size_t)(k0 + kk) * 256 + c0);  // coalesced
#pragma unroll
      for (int r = 0; r < 8; ++r) {
        float ar = (kk == 0) ? a[r].x : (kk == 1) ? a[r].y : (kk == 2) ? a[r].z : a[r].w;
        acc[r].x += ar * wv.x;
        acc[r].y += ar * wv.y;
        acc[r].z += ar * wv.z;
        acc[r].w += ar * wv.w;
      }
    }
  }
#pragma unroll
  for (int r = 0; r < 8; ++r) {
    int m = m0 + r;
    if (m < NN) *(float4*)(Z + (size_t)m * 256 + c0) = acc[r];  // coalesced
  }
}

// ---------------- aggregation hop ----------------
// half-wave (32 lanes x float4) per node:
// agg = dinv[v] * ( sum_in dinv[src]*in[src] + dinv[v]*in[v] )
// Edge indices + dinv prefetched 32-at-a-time cooperatively (coalesced) and
// broadcast via width-32 shuffles; feature gathers 2-way unrolled.
// LAST=0: out = agg; hidden = in[v] + agg
// LAST=1: hidden += agg, then fused row-L2-normalize (no out store)
template <int LAST>
__global__ __launch_bounds__(256) void k_agg(const float* __restrict__ in,
                                             float* __restrict__ out,
                                             float* __restrict__ hidden,
                                             const float* __restrict__ dinv,
                                             const int* __restrict__ colptr,
                                             const int* __restrict__ csrc) {
  int v = (blockIdx.x * 256 + threadIdx.x) >> 5;
  int l = threadIdx.x & 31;
  if (v >= NN) return;
  float dv = dinv[v];
  float4 sv = *(const float4*)(in + (size_t)v * 128 + l * 4);
  float ax = sv.x * dv, ay = sv.y * dv, az = sv.z * dv, aw = sv.w * dv;
  int s = colptr[v], e = colptr[v + 1];
  for (int p0 = s; p0 < e; p0 += 32) {
    int cnt = e - p0;
    if (cnt > 32) cnt = 32;
    int myi = (l < cnt) ? csrc[p0 + l] : 0;     // coalesced 128B index load
    float myd = (l < cnt) ? dinv[myi] : 0.0f;   // one dinv gather per edge
    int q = 0;
    for (; q + 1 < cnt; q += 2) {
      int s0 = __shfl(myi, q, 32);
      int s1 = __shfl(myi, q + 1, 32);
      float d0 = __shfl(myd, q, 32);
      float d1 = __shfl(myd, q + 1, 32);
      float4 h0 = *(const float4*)(in + (size_t)s0 * 128 + l * 4);
      float4 h1 = *(const float4*)(in + (size_t)s1 * 128 + l * 4);
      ax += h0.x * d0 + h1.x * d1;
      ay += h0.y * d0 + h1.y * d1;
      az += h0.z * d0 + h1.z * d1;
      aw += h0.w * d0 + h1.w * d1;
    }
    if (q < cnt) {
      int s0 = __shfl(myi, q, 32);
      float d0 = __shfl(myd, q, 32);
      float4 h0 = *(const float4*)(in + (size_t)s0 * 128 + l * 4);
      ax += h0.x * d0;
      ay += h0.y * d0;
      az += h0.z * d0;
      aw += h0.w * d0;
    }
  }
  ax *= dv; ay *= dv; az *= dv; aw *= dv;
  if (!LAST) {
    float4 o4 = {ax, ay, az, aw};
    *(float4*)(out + (size_t)v * 128 + l * 4) = o4;
    float4 hd = {sv.x + ax, sv.y + ay, sv.z + az, sv.w + aw};
    *(float4*)(hidden + (size_t)v * 128 + l * 4) = hd;
  } else {
    float4 hp = *(const float4*)(hidden + (size_t)v * 128 + l * 4);
    float4 hd = {hp.x + ax, hp.y + ay, hp.z + az, hp.w + aw};
    // fused F.normalize: half-wave owns the whole 128-dim row
    float ss = hd.x * hd.x + hd.y * hd.y + hd.z * hd.z + hd.w * hd.w;
#pragma unroll
    for (int d = 1; d < 32; d <<= 1) ss += __shfl_xor(ss, d, 64);  // masks 1..16
    float sc = 1.0f / fmaxf(sqrtf(ss), 1e-12f);
    float4 r = {hd.x * sc, hd.y * sc, hd.z * sc, hd.w * sc};
    *(float4*)(hidden + (size_t)v * 128 + l * 4) = r;
  }
}

// ---------------- edge head reduce ----------------
// 16 lanes per edge, each lane covers o = l*4..+3 and o = 64+l*4..+3:
// pred[e] = b_l2 + sum_{o<128} Wl2[o]*relu(bl1[o]+Z[i][o]+Z[j][128+o])
__global__ __launch_bounds__(256) void k_edge(const float* __restrict__ Z,
                                              const float* __restrict__ bl1,
                                              const float* __restrict__ Wl2,
                                              const float* __restrict__ bl2,
                                              const int* __restrict__ eli,
                                              float* __restrict__ pred) {
  int g = blockIdx.x * 256 + threadIdx.x;
  int e = g >> 4;
  int l = g & 15;
  if (e >= NL) return;
  int i = eli[e], j = eli[NL + e];
  const float* zi = Z + (size_t)i * 256;
  const float* zj = Z + (size_t)j * 256 + 128;
  float s = 0.0f;
#pragma unroll
  for (int half = 0; half < 2; ++half) {
    int o = half * 64 + l * 4;
    float4 za = *(const float4*)(zi + o);
    float4 zb = *(const float4*)(zj + o);
    float4 bb = *(const float4*)(bl1 + o);
    float4 w2 = *(const float4*)(Wl2 + o);
    s += fmaxf(za.x + zb.x + bb.x, 0.f) * w2.x
       + fmaxf(za.y + zb.y + bb.y, 0.f) * w2.y
       + fmaxf(za.z + zb.z + bb.z, 0.f) * w2.z
       + fmaxf(za.w + zb.w + bb.w, 0.f) * w2.w;
  }
#pragma unroll
  for (int d = 1; d < 16; d <<= 1) s += __shfl_xor(s, d, 64);
  if (l == 0) pred[e] = s + bl2[0];
}

extern "C" void kernel_launch(void* const* d_in, const int* in_sizes, int n_in,
                              void* d_out, int out_size, void* d_ws, size_t ws_size,
                              hipStream_t stream) {
  const float* x   = (const float*)d_in[0];
  const float* W1  = (const float*)d_in[1];
  const float* b1  = (const float*)d_in[2];
  const float* Wl1 = (const float*)d_in[3];
  const float* bl1 = (const float*)d_in[4];
  const float* Wl2 = (const float*)d_in[5];
  const float* bl2 = (const float*)d_in[6];
  const int* ei    = (const int*)d_in[7];
  const int* eli   = (const int*)d_in[8];
  float* pred = (float*)d_out;

  char* ws = (char*)d_ws;
  size_t off = 0;
  auto alloc = [&](size_t bytes) {
    void* p = ws + off;
    off = (off + bytes + 255) & ~(size_t)255;
    return p;
  };
  float* dinv  = (float*)alloc(NN * 4);
  int* deg     = (int*)alloc(NN * 4);
  int* indeg   = (int*)alloc(NN * 4);
  int* colptr  = (int*)alloc((NN + 1) * 4);
  int* cursor  = (int*)alloc(NN * 4);
  int* bsum    = (int*)alloc(NB * 4);
  int* boff    = (int*)alloc(NB * 4);
  int* csrc    = (int*)alloc((size_t)NE * 4);
  float* WT1   = (float*)alloc(128 * 128 * 4);
  float* WTl1  = (float*)alloc(128 * 256 * 4);
  float* h     = (float*)alloc((size_t)NN * 128 * 4);
  float* hn    = (float*)alloc((size_t)NN * 128 * 4);  // contiguous after h
  float* hid   = (float*)alloc((size_t)NN * 128 * 4);
  float* Z     = h;  // 50000x256 f32 = 51.2MB overlays dead h+hn after agg

  k_init<<<NB, 256, 0, stream>>>(deg, indeg);
  k_count<<<(NE + 255) / 256, 256, 0, stream>>>(ei, deg, indeg);
  k_blocksum<<<NB, 256, 0, stream>>>(indeg, deg, dinv, bsum);
  k_scan_bsums<<<1, 256, 0, stream>>>(bsum, boff);
  k_colptr<<<NB, 256, 0, stream>>>(indeg, boff, colptr, cursor);
  k_fill<<<(NE + 255) / 256, 256, 0, stream>>>(ei, cursor, csrc);
  k_transW<<<192, 256, 0, stream>>>(W1, Wl1, WT1, WTl1);

  const int GB = (NN + 31) / 32;  // 1563
  k_gemm_h<<<GB, 256, 0, stream>>>(x, WT1, b1, h);

  k_agg<0><<<(NN * 32 + 255) / 256, 256, 0, stream>>>(h, hn, hid, dinv, colptr, csrc);
  k_agg<1><<<(NN * 32 + 255) / 256, 256, 0, stream>>>(hn, nullptr, hid, dinv, colptr, csrc);

  k_gemm_z<<<GB, 256, 0, stream>>>(hid, WTl1, Z);

  k_edge<<<(NL * 16 + 255) / 256, 256, 0, stream>>>(Z, bl1, Wl2, bl2, eli, pred);
}